// Round 4
// baseline (376.851 us; speedup 1.0000x reference)
//
#include <hip/hip_runtime.h>
#include <stdint.h>

// Attention fwd, B=2 H=12 S=2048 D=64, f32 in/out, outputs (out, p_attn).
// R4: barrier-minimal restructure. K and Q are loaded DIRECTLY from global
// (L2-resident) into MFMA fragment layout per wave — no K/Q LDS, no staging
// barriers. Sweep 1 has ZERO barriers. Sweep 2 has ONE barrier per tile
// (V double-buffer invariant). Conversions via native (__bf16) casts.

#define H_HEADS 12
#define S_LEN   2048
#define NKT     32          // S/64 K-tiles
#define L2E     1.4426950408889634f
#define NEGL2E  (-1.4426950408889634e9f)   // -1e9 * log2(e)

typedef __bf16 bf16x8 __attribute__((ext_vector_type(8)));
typedef float  f32x4  __attribute__((ext_vector_type(4)));

#define MFMA(a, b, c) __builtin_amdgcn_mfma_f32_16x16x32_bf16((a), (b), (c), 0, 0, 0)

__global__ __launch_bounds__(256, 3)
void attn_fused(const float* __restrict__ Qg, const float* __restrict__ Kg,
                const float* __restrict__ Vg, const int* __restrict__ Mg,
                float* __restrict__ Og, float* __restrict__ Pg)
{
    __shared__ __align__(16) unsigned short VS[2][4096];  // 16 KB V double buffer (B-frag layout)
    __shared__ __align__(16) unsigned short PS[4096];     // 8 KB P staging (bf16, swizzled rows)
    __shared__ float madd[S_LEN];                         // 8 KB mask addend (pre-scaled by log2e)

    const int tid  = threadIdx.x;
    const int lane = tid & 63;
    const int w    = tid >> 6;       // wave 0..3 -> q rows [w*16, w*16+16)
    const int l15  = lane & 15;
    const int g    = lane >> 4;      // 0..3

    // XCD swizzle: 768 blocks, 8 XCDs, 96 blocks/XCD = 3 whole heads per XCD
    const int bid = blockIdx.x;
    const int wgs = (bid & 7) * 96 + (bid >> 3);
    const int bh  = wgs >> 5;        // 0..23
    const int qt  = wgs & 31;        // 0..31
    const int b   = bh / H_HEADS;
    const int q0  = qt * 64;

    const size_t headoff = (size_t)bh * (S_LEN * 64);
    const float* Qp = Qg + headoff;
    const float* Kp = Kg + headoff;
    const float* Vp = Vg + headoff;

    // ---- mask -> LDS (whole row, shared by all tiles) ----
    #pragma unroll
    for (int i = 0; i < 8; ++i) {
        int k = i * 256 + tid;
        madd[k] = Mg[b * S_LEN + k] ? 0.0f : NEGL2E;
    }

    // ---- Q fragments direct from global: row q0+w*16+l15, dims kk*32+g*8+j, x0.125 ----
    bf16x8 aqh[2], aql[2];
    {
        const float* qrow = Qp + (size_t)(q0 + w * 16 + l15) * 64 + g * 8;
        #pragma unroll
        for (int kk = 0; kk < 2; ++kk) {
            float4 qa = *reinterpret_cast<const float4*>(qrow + kk * 32);
            float4 qb = *reinterpret_cast<const float4*>(qrow + kk * 32 + 4);
            float qs0 = qa.x * 0.125f, qs1 = qa.y * 0.125f, qs2 = qa.z * 0.125f, qs3 = qa.w * 0.125f;
            float qs4 = qb.x * 0.125f, qs5 = qb.y * 0.125f, qs6 = qb.z * 0.125f, qs7 = qb.w * 0.125f;
            __bf16 h0 = (__bf16)qs0, h1 = (__bf16)qs1, h2 = (__bf16)qs2, h3 = (__bf16)qs3;
            __bf16 h4 = (__bf16)qs4, h5 = (__bf16)qs5, h6 = (__bf16)qs6, h7 = (__bf16)qs7;
            aqh[kk][0] = h0; aqh[kk][1] = h1; aqh[kk][2] = h2; aqh[kk][3] = h3;
            aqh[kk][4] = h4; aqh[kk][5] = h5; aqh[kk][6] = h6; aqh[kk][7] = h7;
            aql[kk][0] = (__bf16)(qs0 - (float)h0); aql[kk][1] = (__bf16)(qs1 - (float)h1);
            aql[kk][2] = (__bf16)(qs2 - (float)h2); aql[kk][3] = (__bf16)(qs3 - (float)h3);
            aql[kk][4] = (__bf16)(qs4 - (float)h4); aql[kk][5] = (__bf16)(qs5 - (float)h5);
            aql[kk][6] = (__bf16)(qs6 - (float)h6); aql[kk][7] = (__bf16)(qs7 - (float)h7);
        }
    }
    __syncthreads();   // madd ready (the only barrier before sweep 2)

    // ================= sweep 1: l = sum over keys of exp(s) — NO barriers =================
    float ls0 = 0.f, ls1 = 0.f, ls2 = 0.f, ls3 = 0.f;
    for (int kt = 0; kt < NKT; ++kt) {
        const float* kb = Kp + (size_t)(kt * 64 + l15) * 64 + g * 8;
        #pragma unroll
        for (int ct = 0; ct < 4; ++ct) {
            const float* kr = kb + ct * 16 * 64;
            float4 ka = *reinterpret_cast<const float4*>(kr);
            float4 kc = *reinterpret_cast<const float4*>(kr + 4);
            float4 kd = *reinterpret_cast<const float4*>(kr + 32);
            float4 ke = *reinterpret_cast<const float4*>(kr + 36);
            bf16x8 k0, k1;
            k0[0] = (__bf16)ka.x; k0[1] = (__bf16)ka.y; k0[2] = (__bf16)ka.z; k0[3] = (__bf16)ka.w;
            k0[4] = (__bf16)kc.x; k0[5] = (__bf16)kc.y; k0[6] = (__bf16)kc.z; k0[7] = (__bf16)kc.w;
            k1[0] = (__bf16)kd.x; k1[1] = (__bf16)kd.y; k1[2] = (__bf16)kd.z; k1[3] = (__bf16)kd.w;
            k1[4] = (__bf16)ke.x; k1[5] = (__bf16)ke.y; k1[6] = (__bf16)ke.z; k1[7] = (__bf16)ke.w;
            f32x4 acc = {0.f, 0.f, 0.f, 0.f};
            acc = MFMA(aqh[0], k0, acc);
            acc = MFMA(aqh[1], k1, acc);
            float ma = madd[kt * 64 + ct * 16 + l15];
            ls0 += __builtin_amdgcn_exp2f(__builtin_fmaf(acc[0], L2E, ma));
            ls1 += __builtin_amdgcn_exp2f(__builtin_fmaf(acc[1], L2E, ma));
            ls2 += __builtin_amdgcn_exp2f(__builtin_fmaf(acc[2], L2E, ma));
            ls3 += __builtin_amdgcn_exp2f(__builtin_fmaf(acc[3], L2E, ma));
        }
    }
    #pragma unroll
    for (int m = 1; m <= 8; m <<= 1) {
        ls0 += __shfl_xor(ls0, m);
        ls1 += __shfl_xor(ls1, m);
        ls2 += __shfl_xor(ls2, m);
        ls3 += __shfl_xor(ls3, m);
    }
    const float li0 = 1.0f / ls0, li1 = 1.0f / ls1, li2 = 1.0f / ls2, li3 = 1.0f / ls3;

    // ================= sweep 2: p = exp(s)/l (split-bf16 K), PV — ONE barrier/tile =================
    f32x4 o0 = {0,0,0,0}, o1 = {0,0,0,0}, o2 = {0,0,0,0}, o3 = {0,0,0,0};
    float* Pout = Pg + ((size_t)bh * S_LEN + q0) * S_LEN;

    // prologue: stage V tile 0 into VS[0]
    {
        #pragma unroll
        for (int gi = 0; gi < 2; ++gi) {
            int gv = w + gi * 4;
            const float* vsrc = Vp + (size_t)(gv * 8) * 64 + lane;
            bf16x8 v8;
            v8[0] = (__bf16)vsrc[0];       v8[1] = (__bf16)vsrc[64];
            v8[2] = (__bf16)vsrc[128];     v8[3] = (__bf16)vsrc[192];
            v8[4] = (__bf16)vsrc[256];     v8[5] = (__bf16)vsrc[320];
            v8[6] = (__bf16)vsrc[384];     v8[7] = (__bf16)vsrc[448];
            *reinterpret_cast<bf16x8*>(reinterpret_cast<char*>(VS[0]) + (gv * 64 + lane) * 16) = v8;
        }
    }
    __syncthreads();

    for (int kt = 0; kt < NKT; ++kt) {
        // ---- QK^T (split-bf16, K direct from global), exp, P->LDS + NT p-stores ----
        {
            const float* kb = Kp + (size_t)(kt * 64 + l15) * 64 + g * 8;
            #pragma unroll
            for (int ct = 0; ct < 4; ++ct) {
                const float* kr = kb + ct * 16 * 64;
                float4 ka = *reinterpret_cast<const float4*>(kr);
                float4 kc = *reinterpret_cast<const float4*>(kr + 4);
                float4 kd = *reinterpret_cast<const float4*>(kr + 32);
                float4 ke = *reinterpret_cast<const float4*>(kr + 36);
                bf16x8 kh0, kh1, kl0, kl1;
                {
                    __bf16 h0 = (__bf16)ka.x, h1 = (__bf16)ka.y, h2 = (__bf16)ka.z, h3 = (__bf16)ka.w;
                    __bf16 h4 = (__bf16)kc.x, h5 = (__bf16)kc.y, h6 = (__bf16)kc.z, h7 = (__bf16)kc.w;
                    kh0[0] = h0; kh0[1] = h1; kh0[2] = h2; kh0[3] = h3;
                    kh0[4] = h4; kh0[5] = h5; kh0[6] = h6; kh0[7] = h7;
                    kl0[0] = (__bf16)(ka.x - (float)h0); kl0[1] = (__bf16)(ka.y - (float)h1);
                    kl0[2] = (__bf16)(ka.z - (float)h2); kl0[3] = (__bf16)(ka.w - (float)h3);
                    kl0[4] = (__bf16)(kc.x - (float)h4); kl0[5] = (__bf16)(kc.y - (float)h5);
                    kl0[6] = (__bf16)(kc.z - (float)h6); kl0[7] = (__bf16)(kc.w - (float)h7);
                }
                {
                    __bf16 h0 = (__bf16)kd.x, h1 = (__bf16)kd.y, h2 = (__bf16)kd.z, h3 = (__bf16)kd.w;
                    __bf16 h4 = (__bf16)ke.x, h5 = (__bf16)ke.y, h6 = (__bf16)ke.z, h7 = (__bf16)ke.w;
                    kh1[0] = h0; kh1[1] = h1; kh1[2] = h2; kh1[3] = h3;
                    kh1[4] = h4; kh1[5] = h5; kh1[6] = h6; kh1[7] = h7;
                    kl1[0] = (__bf16)(kd.x - (float)h0); kl1[1] = (__bf16)(kd.y - (float)h1);
                    kl1[2] = (__bf16)(kd.z - (float)h2); kl1[3] = (__bf16)(kd.w - (float)h3);
                    kl1[4] = (__bf16)(ke.x - (float)h4); kl1[5] = (__bf16)(ke.y - (float)h5);
                    kl1[6] = (__bf16)(ke.z - (float)h6); kl1[7] = (__bf16)(ke.w - (float)h7);
                }
                f32x4 acc = {0.f, 0.f, 0.f, 0.f};
                acc = MFMA(aqh[0], kh0, acc);
                acc = MFMA(aql[0], kh0, acc);
                acc = MFMA(aqh[0], kl0, acc);
                acc = MFMA(aqh[1], kh1, acc);
                acc = MFMA(aql[1], kh1, acc);
                acc = MFMA(aqh[1], kl1, acc);

                float ma = madd[kt * 64 + ct * 16 + l15];
                float p0 = __builtin_amdgcn_exp2f(__builtin_fmaf(acc[0], L2E, ma)) * li0;
                float p1 = __builtin_amdgcn_exp2f(__builtin_fmaf(acc[1], L2E, ma)) * li1;
                float p2 = __builtin_amdgcn_exp2f(__builtin_fmaf(acc[2], L2E, ma)) * li2;
                float p3 = __builtin_amdgcn_exp2f(__builtin_fmaf(acc[3], L2E, ma)) * li3;

                // NT global p_attn stores
                float* Prow = Pout + (size_t)(w * 16 + g * 4) * S_LEN + (size_t)kt * 64;
                int col = ct * 16 + l15;
                __builtin_nontemporal_store(p0, Prow + col);
                __builtin_nontemporal_store(p1, Prow + S_LEN + col);
                __builtin_nontemporal_store(p2, Prow + 2 * S_LEN + col);
                __builtin_nontemporal_store(p3, Prow + 3 * S_LEN + col);

                // LDS P (bf16, A-fragment layout rows, swizzled) — wave-local
                int pb = (w * 16 + g * 4) * 128 + (ct * 16 + l15) * 2;
                *reinterpret_cast<unsigned short*>(reinterpret_cast<char*>(PS) + ((pb)       ^ (((g * 4 + 0) & 7) << 4))) = __builtin_bit_cast(unsigned short, (__bf16)p0);
                *reinterpret_cast<unsigned short*>(reinterpret_cast<char*>(PS) + ((pb + 128) ^ (((g * 4 + 1) & 7) << 4))) = __builtin_bit_cast(unsigned short, (__bf16)p1);
                *reinterpret_cast<unsigned short*>(reinterpret_cast<char*>(PS) + ((pb + 256) ^ (((g * 4 + 2) & 7) << 4))) = __builtin_bit_cast(unsigned short, (__bf16)p2);
                *reinterpret_cast<unsigned short*>(reinterpret_cast<char*>(PS) + ((pb + 384) ^ (((g * 4 + 3) & 7) << 4))) = __builtin_bit_cast(unsigned short, (__bf16)p3);
            }
        }

        // ---- stage V tile kt+1 into VS[(kt+1)&1] (single-barrier double-buffer) ----
        {
            int ktn = (kt + 1 < NKT) ? kt + 1 : NKT - 1;
            #pragma unroll
            for (int gi = 0; gi < 2; ++gi) {
                int gv = w + gi * 4;
                const float* vsrc = Vp + (size_t)(ktn * 64 + gv * 8) * 64 + lane;
                bf16x8 v8;
                v8[0] = (__bf16)vsrc[0];       v8[1] = (__bf16)vsrc[64];
                v8[2] = (__bf16)vsrc[128];     v8[3] = (__bf16)vsrc[192];
                v8[4] = (__bf16)vsrc[256];     v8[5] = (__bf16)vsrc[320];
                v8[6] = (__bf16)vsrc[384];     v8[7] = (__bf16)vsrc[448];
                *reinterpret_cast<bf16x8*>(reinterpret_cast<char*>(VS[(kt + 1) & 1]) + (gv * 64 + lane) * 16) = v8;
            }
        }

        // ---- PV from VS[kt&1]: out += P(16x64) * V(64x64) ----
        {
            const char* vbuf = reinterpret_cast<const char*>(VS[kt & 1]);
            #pragma unroll
            for (int kk = 0; kk < 2; ++kk) {
                int abyte = (((w * 16 + l15) * 128 + kk * 64 + g * 16) ^ ((l15 & 7) << 4));
                bf16x8 ap = *reinterpret_cast<const bf16x8*>(reinterpret_cast<const char*>(PS) + abyte);
                int vb = ((kk * 4 + g) * 64 + l15) * 16;
                bf16x8 bv0 = *reinterpret_cast<const bf16x8*>(vbuf + vb);
                bf16x8 bv1 = *reinterpret_cast<const bf16x8*>(vbuf + vb + 256);
                bf16x8 bv2 = *reinterpret_cast<const bf16x8*>(vbuf + vb + 512);
                bf16x8 bv3 = *reinterpret_cast<const bf16x8*>(vbuf + vb + 768);
                o0 = MFMA(ap, bv0, o0);
                o1 = MFMA(ap, bv1, o1);
                o2 = MFMA(ap, bv2, o2);
                o3 = MFMA(ap, bv3, o3);
            }
        }
        __syncthreads();   // the only barrier per tile
    }

    // ---------------- epilogue: out ----------------
    {
        float* Ob = Og + headoff + (size_t)(q0 + w * 16 + g * 4) * 64 + l15;
        #pragma unroll
        for (int r = 0; r < 4; ++r) {
            Ob[(size_t)r * 64 + 0]  = o0[r];
            Ob[(size_t)r * 64 + 16] = o1[r];
            Ob[(size_t)r * 64 + 32] = o2[r];
            Ob[(size_t)r * 64 + 48] = o3[r];
        }
    }
}

extern "C" void kernel_launch(void* const* d_in, const int* in_sizes, int n_in,
                              void* d_out, int out_size, void* d_ws, size_t ws_size,
                              hipStream_t stream)
{
    (void)in_sizes; (void)n_in; (void)out_size; (void)d_ws; (void)ws_size;
    const float* Q = (const float*)d_in[0];
    const float* K = (const float*)d_in[1];
    const float* V = (const float*)d_in[2];
    const int*   M = (const int*)d_in[3];
    float* Out = (float*)d_out;
    float* P   = Out + (size_t)2 * H_HEADS * S_LEN * 64;   // p_attn after out

    attn_fused<<<dim3(768), 256, 0, stream>>>(Q, K, V, M, Out, P);
}

// Round 5
// 162.886 us; speedup vs baseline: 2.3136x; 2.3136x over previous
//
#include <hip/hip_runtime.h>
#include <stdint.h>

// Attention fwd, B=2 H=12 S=2048 D=64, f32 in/out, outputs (out, p_attn).
// R5: R3 structure (LDS-staged K/V, reg prefetch, XCD swizzle, NT p-stores)
// with raw lgkm-only barriers: s_waitcnt lgkmcnt(0); s_barrier — NO vmcnt
// drain at inner-loop barriers (T4: stores/loads stay in flight across
// barriers; only LDS ordering is enforced). p-stores inline at p-compute.

#define H_HEADS 12
#define S_LEN   2048
#define NKT     32          // S/64 K-tiles
#define L2E     1.4426950408889634f
#define NEGL2E  (-1.4426950408889634e9f)   // -1e9 * log2(e)

typedef __bf16 bf16x8 __attribute__((ext_vector_type(8)));
typedef float  f32x4  __attribute__((ext_vector_type(4)));

static __device__ __forceinline__ unsigned short f2bf(float f) {
    uint32_t u = __builtin_bit_cast(uint32_t, f);
    u += 0x7fffu + ((u >> 16) & 1u);            // RNE
    return (unsigned short)(u >> 16);
}
static __device__ __forceinline__ float bf2f(unsigned short h) {
    uint32_t u = (uint32_t)h << 16;
    return __builtin_bit_cast(float, u);
}

#define MFMA(a, b, c) __builtin_amdgcn_mfma_f32_16x16x32_bf16((a), (b), (c), 0, 0, 0)

// Raw barrier: enforce LDS ordering only. No vmcnt drain (stores/loads keep
// flying). "memory" clobber pins LDS op order around it.
#define BAR_LGKM() asm volatile("s_waitcnt lgkmcnt(0)\n\ts_barrier" ::: "memory")

__global__ __launch_bounds__(256, 4)
void attn_fused(const float* __restrict__ Qg, const float* __restrict__ Kg,
                const float* __restrict__ Vg, const int* __restrict__ Mg,
                float* __restrict__ Og, float* __restrict__ Pg)
{
    // bufA: bytes [0,8192) = Qhi staging -> later V (B-frag layout)
    //       bytes [8192,16384) = Qlo staging -> later P (bf16, swizzled rows)
    __shared__ __align__(16) unsigned short bufA[8192];   // 16 KB
    __shared__ __align__(16) unsigned short KhS[4096];    // 8 KB, swizzled
    __shared__ __align__(16) unsigned short KlS[4096];    // 8 KB, swizzled
    __shared__ float madd_s[64];                          // 256 B per-tile mask addend

    const int tid  = threadIdx.x;
    const int lane = tid & 63;
    const int w    = tid >> 6;       // wave 0..3 -> q rows [w*16, w*16+16)
    const int l15  = lane & 15;
    const int g    = lane >> 4;      // 0..3

    // XCD swizzle: 768 blocks, 8 XCDs, 96 blocks/XCD = 3 whole heads per XCD
    const int bid = blockIdx.x;
    const int wgs = (bid & 7) * 96 + (bid >> 3);
    const int bh  = wgs >> 5;        // 0..23
    const int qt  = wgs & 31;        // 0..31
    const int b   = bh / H_HEADS;
    const int q0  = qt * 64;

    const size_t headoff = (size_t)bh * (S_LEN * 64);
    const float* Qp = Qg + headoff + (size_t)q0 * 64;
    const float* Kp = Kg + headoff;
    const float* Vp = Vg + headoff;
    const int*   Mp = Mg + b * S_LEN;

    // ---------------- stage Q (x0.125, exact in bf16) as hi/lo ----------------
    {
        const float4* src = reinterpret_cast<const float4*>(Qp);
        #pragma unroll
        for (int i = 0; i < 4; ++i) {
            int e   = i * 256 + tid;              // float4 index in 64x64 tile
            int row = e >> 4;
            int byte = (row * 128 + (e & 15) * 8) ^ ((row & 7) << 4);
            float4 v = src[e];
            float f0 = v.x * 0.125f, f1 = v.y * 0.125f, f2 = v.z * 0.125f, f3 = v.w * 0.125f;
            unsigned short h0 = f2bf(f0), h1 = f2bf(f1), h2 = f2bf(f2), h3 = f2bf(f3);
            unsigned short u0 = f2bf(f0 - bf2f(h0)), u1 = f2bf(f1 - bf2f(h1));
            unsigned short u2 = f2bf(f2 - bf2f(h2)), u3 = f2bf(f3 - bf2f(h3));
            *reinterpret_cast<uint2*>(reinterpret_cast<char*>(bufA) + byte) =
                make_uint2((unsigned)h0 | ((unsigned)h1 << 16), (unsigned)h2 | ((unsigned)h3 << 16));
            *reinterpret_cast<uint2*>(reinterpret_cast<char*>(bufA) + 8192 + byte) =
                make_uint2((unsigned)u0 | ((unsigned)u1 << 16), (unsigned)u2 | ((unsigned)u3 << 16));
        }
    }
    __syncthreads();

    // ---------------- hoist Q fragments (A-operand) ----------------
    bf16x8 aqh[2], aql[2];
    {
        const int rb = (w * 16 + l15) * 128;
        const int sw = (l15 & 7) << 4;
        #pragma unroll
        for (int kk = 0; kk < 2; ++kk) {
            int byte = (rb + kk * 64 + g * 16) ^ sw;
            aqh[kk] = *reinterpret_cast<const bf16x8*>(reinterpret_cast<const char*>(bufA) + byte);
            aql[kk] = *reinterpret_cast<const bf16x8*>(reinterpret_cast<const char*>(bufA) + 8192 + byte);
        }
    }

    float4 kq[4];       // K-tile prefetch registers
    float  vv[16];      // V-tile prefetch registers
    float  mv = 0.f;    // mask prefetch (tid < 64)

    // ================= sweep 1: l = sum over keys of exp(s) =================
    // prologue: load tile 0, write it, issue tile 1
    {
        const float4* src = reinterpret_cast<const float4*>(Kp);
        kq[0] = src[tid]; kq[1] = src[256 + tid]; kq[2] = src[512 + tid]; kq[3] = src[768 + tid];
        if (tid < 64) mv = Mp[tid] ? 0.0f : NEGL2E;
    }
    {
        #pragma unroll
        for (int i = 0; i < 4; ++i) {
            int e = i * 256 + tid, row = e >> 4;
            int byte = (row * 128 + (e & 15) * 8) ^ ((row & 7) << 4);
            float4 v = kq[i];
            *reinterpret_cast<uint2*>(reinterpret_cast<char*>(KhS) + byte) =
                make_uint2((unsigned)f2bf(v.x) | ((unsigned)f2bf(v.y) << 16),
                           (unsigned)f2bf(v.z) | ((unsigned)f2bf(v.w) << 16));
        }
        if (tid < 64) madd_s[tid] = mv;
    }
    {
        const float4* src = reinterpret_cast<const float4*>(Kp + 4096);
        kq[0] = src[tid]; kq[1] = src[256 + tid]; kq[2] = src[512 + tid]; kq[3] = src[768 + tid];
        mv = 0.f;
        if (tid < 64) mv = Mp[64 + tid] ? 0.0f : NEGL2E;
    }
    __syncthreads();

    float ls0 = 0.f, ls1 = 0.f, ls2 = 0.f, ls3 = 0.f;
    for (int kt = 0; kt < NKT; ++kt) {
        // ---- compute tile kt from LDS ----
        {
            const int sw = (l15 & 7) << 4;
            #pragma unroll
            for (int ct = 0; ct < 4; ++ct) {
                f32x4 acc = {0.f, 0.f, 0.f, 0.f};
                #pragma unroll
                for (int kk = 0; kk < 2; ++kk) {
                    int byte = ((ct * 16 + l15) * 128 + kk * 64 + g * 16) ^ sw;
                    bf16x8 bk = *reinterpret_cast<const bf16x8*>(reinterpret_cast<const char*>(KhS) + byte);
                    acc = MFMA(aqh[kk], bk, acc);
                }
                float ma = madd_s[ct * 16 + l15];
                ls0 += __builtin_amdgcn_exp2f(__builtin_fmaf(acc[0], L2E, ma));
                ls1 += __builtin_amdgcn_exp2f(__builtin_fmaf(acc[1], L2E, ma));
                ls2 += __builtin_amdgcn_exp2f(__builtin_fmaf(acc[2], L2E, ma));
                ls3 += __builtin_amdgcn_exp2f(__builtin_fmaf(acc[3], L2E, ma));
            }
        }
        BAR_LGKM();        // reads(kt) done -> writers may proceed; NO vmcnt drain
        if (kt + 1 < NKT) {
            // ---- write tile kt+1 from regs (use-site vmcnt waits on kq) ----
            #pragma unroll
            for (int i = 0; i < 4; ++i) {
                int e = i * 256 + tid, row = e >> 4;
                int byte = (row * 128 + (e & 15) * 8) ^ ((row & 7) << 4);
                float4 v = kq[i];
                *reinterpret_cast<uint2*>(reinterpret_cast<char*>(KhS) + byte) =
                    make_uint2((unsigned)f2bf(v.x) | ((unsigned)f2bf(v.y) << 16),
                               (unsigned)f2bf(v.z) | ((unsigned)f2bf(v.w) << 16));
            }
            if (tid < 64) madd_s[tid] = mv;
            BAR_LGKM();    // writes(kt+1) visible -> readers may proceed
            if (kt + 2 < NKT) {
                // ---- issue loads for tile kt+2 (stay in flight across barriers) ----
                const float4* src = reinterpret_cast<const float4*>(Kp + (size_t)(kt + 2) * 4096);
                kq[0] = src[tid]; kq[1] = src[256 + tid]; kq[2] = src[512 + tid]; kq[3] = src[768 + tid];
                mv = 0.f;
                if (tid < 64) mv = Mp[(kt + 2) * 64 + tid] ? 0.0f : NEGL2E;
            }
        }
    }
    #pragma unroll
    for (int m = 1; m <= 8; m <<= 1) {
        ls0 += __shfl_xor(ls0, m);
        ls1 += __shfl_xor(ls1, m);
        ls2 += __shfl_xor(ls2, m);
        ls3 += __shfl_xor(ls3, m);
    }
    const float li0 = 1.0f / ls0, li1 = 1.0f / ls1, li2 = 1.0f / ls2, li3 = 1.0f / ls3;

    // ================= sweep 2: p = exp(s)/l (split-bf16 scores), PV =================
    f32x4 o0 = {0,0,0,0}, o1 = {0,0,0,0}, o2 = {0,0,0,0}, o3 = {0,0,0,0};
    float* Pout = Pg + ((size_t)bh * S_LEN + q0) * S_LEN;

    // prologue: load tile 0, write it, issue tile 1
    {
        const float4* src = reinterpret_cast<const float4*>(Kp);
        kq[0] = src[tid]; kq[1] = src[256 + tid]; kq[2] = src[512 + tid]; kq[3] = src[768 + tid];
        const float* vsrc  = Vp + (size_t)(w * 8) * 64 + lane;
        const float* vsrc2 = Vp + (size_t)((w + 4) * 8) * 64 + lane;
        #pragma unroll
        for (int j = 0; j < 8; ++j) { vv[j] = vsrc[j * 64]; vv[8 + j] = vsrc2[j * 64]; }
        mv = 0.f;
        if (tid < 64) mv = Mp[tid] ? 0.0f : NEGL2E;
    }
    {
        #pragma unroll
        for (int i = 0; i < 4; ++i) {
            int e = i * 256 + tid, row = e >> 4;
            int byte = (row * 128 + (e & 15) * 8) ^ ((row & 7) << 4);
            float4 v = kq[i];
            unsigned short h0 = f2bf(v.x), h1 = f2bf(v.y), h2 = f2bf(v.z), h3 = f2bf(v.w);
            *reinterpret_cast<uint2*>(reinterpret_cast<char*>(KhS) + byte) =
                make_uint2((unsigned)h0 | ((unsigned)h1 << 16), (unsigned)h2 | ((unsigned)h3 << 16));
            *reinterpret_cast<uint2*>(reinterpret_cast<char*>(KlS) + byte) =
                make_uint2((unsigned)f2bf(v.x - bf2f(h0)) | ((unsigned)f2bf(v.y - bf2f(h1)) << 16),
                           (unsigned)f2bf(v.z - bf2f(h2)) | ((unsigned)f2bf(v.w - bf2f(h3)) << 16));
        }
        #pragma unroll
        for (int gi = 0; gi < 2; ++gi) {
            int gv = w + gi * 4;
            unsigned short c0 = f2bf(vv[gi*8+0]), c1 = f2bf(vv[gi*8+1]), c2 = f2bf(vv[gi*8+2]), c3 = f2bf(vv[gi*8+3]);
            unsigned short c4 = f2bf(vv[gi*8+4]), c5 = f2bf(vv[gi*8+5]), c6 = f2bf(vv[gi*8+6]), c7 = f2bf(vv[gi*8+7]);
            *reinterpret_cast<uint4*>(reinterpret_cast<char*>(bufA) + (gv * 64 + lane) * 16) =
                make_uint4((unsigned)c0 | ((unsigned)c1 << 16), (unsigned)c2 | ((unsigned)c3 << 16),
                           (unsigned)c4 | ((unsigned)c5 << 16), (unsigned)c6 | ((unsigned)c7 << 16));
        }
        if (tid < 64) madd_s[tid] = mv;
    }
    {
        const float4* src = reinterpret_cast<const float4*>(Kp + 4096);
        kq[0] = src[tid]; kq[1] = src[256 + tid]; kq[2] = src[512 + tid]; kq[3] = src[768 + tid];
        const float* vsrc  = Vp + (size_t)(64 + w * 8) * 64 + lane;
        const float* vsrc2 = Vp + (size_t)(64 + (w + 4) * 8) * 64 + lane;
        #pragma unroll
        for (int j = 0; j < 8; ++j) { vv[j] = vsrc[j * 64]; vv[8 + j] = vsrc2[j * 64]; }
        mv = 0.f;
        if (tid < 64) mv = Mp[64 + tid] ? 0.0f : NEGL2E;
    }
    __syncthreads();

    for (int kt = 0; kt < NKT; ++kt) {
        // ---- compute tile kt: QK^T, exp, p-stores (NT, no drain), P->LDS, PV ----
        {
            const int sw = (l15 & 7) << 4;
            #pragma unroll
            for (int ct = 0; ct < 4; ++ct) {
                f32x4 acc = {0.f, 0.f, 0.f, 0.f};
                #pragma unroll
                for (int kk = 0; kk < 2; ++kk) {
                    int byte = ((ct * 16 + l15) * 128 + kk * 64 + g * 16) ^ sw;
                    bf16x8 bh_ = *reinterpret_cast<const bf16x8*>(reinterpret_cast<const char*>(KhS) + byte);
                    bf16x8 bl_ = *reinterpret_cast<const bf16x8*>(reinterpret_cast<const char*>(KlS) + byte);
                    acc = MFMA(aqh[kk], bh_, acc);
                    acc = MFMA(aql[kk], bh_, acc);
                    acc = MFMA(aqh[kk], bl_, acc);
                }
                float ma = madd_s[ct * 16 + l15];
                float p0 = __builtin_amdgcn_exp2f(__builtin_fmaf(acc[0], L2E, ma)) * li0;
                float p1 = __builtin_amdgcn_exp2f(__builtin_fmaf(acc[1], L2E, ma)) * li1;
                float p2 = __builtin_amdgcn_exp2f(__builtin_fmaf(acc[2], L2E, ma)) * li2;
                float p3 = __builtin_amdgcn_exp2f(__builtin_fmaf(acc[3], L2E, ma)) * li3;

                // NT global p_attn stores — never drained inside the loop
                float* Prow = Pout + (size_t)(w * 16 + g * 4) * S_LEN + (size_t)kt * 64;
                int col = ct * 16 + l15;
                __builtin_nontemporal_store(p0, Prow + col);
                __builtin_nontemporal_store(p1, Prow + S_LEN + col);
                __builtin_nontemporal_store(p2, Prow + 2 * S_LEN + col);
                __builtin_nontemporal_store(p3, Prow + 3 * S_LEN + col);

                // LDS P (bf16, A-fragment layout rows, swizzled) — wave-local
                int pb = 8192 + (w * 16 + g * 4) * 128 + (ct * 16 + l15) * 2;
                *reinterpret_cast<unsigned short*>(reinterpret_cast<char*>(bufA) + ((pb)       ^ (((g * 4 + 0) & 7) << 4))) = f2bf(p0);
                *reinterpret_cast<unsigned short*>(reinterpret_cast<char*>(bufA) + ((pb + 128) ^ (((g * 4 + 1) & 7) << 4))) = f2bf(p1);
                *reinterpret_cast<unsigned short*>(reinterpret_cast<char*>(bufA) + ((pb + 256) ^ (((g * 4 + 2) & 7) << 4))) = f2bf(p2);
                *reinterpret_cast<unsigned short*>(reinterpret_cast<char*>(bufA) + ((pb + 384) ^ (((g * 4 + 3) & 7) << 4))) = f2bf(p3);
            }
            // PV: out += P(16x64) * V(64x64)  (wave-local P)
            #pragma unroll
            for (int kk = 0; kk < 2; ++kk) {
                int abyte = 8192 + (((w * 16 + l15) * 128 + kk * 64 + g * 16) ^ ((l15 & 7) << 4));
                bf16x8 ap = *reinterpret_cast<const bf16x8*>(reinterpret_cast<const char*>(bufA) + abyte);
                int vb = ((kk * 4 + g) * 64 + l15) * 16;
                bf16x8 bv0 = *reinterpret_cast<const bf16x8*>(reinterpret_cast<const char*>(bufA) + vb);
                bf16x8 bv1 = *reinterpret_cast<const bf16x8*>(reinterpret_cast<const char*>(bufA) + vb + 256);
                bf16x8 bv2 = *reinterpret_cast<const bf16x8*>(reinterpret_cast<const char*>(bufA) + vb + 512);
                bf16x8 bv3 = *reinterpret_cast<const bf16x8*>(reinterpret_cast<const char*>(bufA) + vb + 768);
                o0 = MFMA(ap, bv0, o0);
                o1 = MFMA(ap, bv1, o1);
                o2 = MFMA(ap, bv2, o2);
                o3 = MFMA(ap, bv3, o3);
            }
        }
        BAR_LGKM();        // reads(kt) done; NO vmcnt drain (p-stores keep flying)
        if (kt + 1 < NKT) {
            // ---- write tile kt+1 (K hi/lo, V, mask) from regs ----
            #pragma unroll
            for (int i = 0; i < 4; ++i) {
                int e = i * 256 + tid, row = e >> 4;
                int byte = (row * 128 + (e & 15) * 8) ^ ((row & 7) << 4);
                float4 v = kq[i];
                unsigned short h0 = f2bf(v.x), h1 = f2bf(v.y), h2 = f2bf(v.z), h3 = f2bf(v.w);
                *reinterpret_cast<uint2*>(reinterpret_cast<char*>(KhS) + byte) =
                    make_uint2((unsigned)h0 | ((unsigned)h1 << 16), (unsigned)h2 | ((unsigned)h3 << 16));
                *reinterpret_cast<uint2*>(reinterpret_cast<char*>(KlS) + byte) =
                    make_uint2((unsigned)f2bf(v.x - bf2f(h0)) | ((unsigned)f2bf(v.y - bf2f(h1)) << 16),
                               (unsigned)f2bf(v.z - bf2f(h2)) | ((unsigned)f2bf(v.w - bf2f(h3)) << 16));
            }
            #pragma unroll
            for (int gi = 0; gi < 2; ++gi) {
                int gv = w + gi * 4;
                unsigned short c0 = f2bf(vv[gi*8+0]), c1 = f2bf(vv[gi*8+1]), c2 = f2bf(vv[gi*8+2]), c3 = f2bf(vv[gi*8+3]);
                unsigned short c4 = f2bf(vv[gi*8+4]), c5 = f2bf(vv[gi*8+5]), c6 = f2bf(vv[gi*8+6]), c7 = f2bf(vv[gi*8+7]);
                *reinterpret_cast<uint4*>(reinterpret_cast<char*>(bufA) + (gv * 64 + lane) * 16) =
                    make_uint4((unsigned)c0 | ((unsigned)c1 << 16), (unsigned)c2 | ((unsigned)c3 << 16),
                               (unsigned)c4 | ((unsigned)c5 << 16), (unsigned)c6 | ((unsigned)c7 << 16));
            }
            if (tid < 64) madd_s[tid] = mv;
            BAR_LGKM();    // writes(kt+1) visible
            if (kt + 2 < NKT) {
                // ---- issue loads for tile kt+2 (fly across the next compute) ----
                const float4* src = reinterpret_cast<const float4*>(Kp + (size_t)(kt + 2) * 4096);
                kq[0] = src[tid]; kq[1] = src[256 + tid]; kq[2] = src[512 + tid]; kq[3] = src[768 + tid];
                const float* vsrc  = Vp + (size_t)((kt + 2) * 64 + w * 8) * 64 + lane;
                const float* vsrc2 = Vp + (size_t)((kt + 2) * 64 + (w + 4) * 8) * 64 + lane;
                #pragma unroll
                for (int j = 0; j < 8; ++j) { vv[j] = vsrc[j * 64]; vv[8 + j] = vsrc2[j * 64]; }
                mv = 0.f;
                if (tid < 64) mv = Mp[(kt + 2) * 64 + tid] ? 0.0f : NEGL2E;
            }
        }
    }

    // ---------------- epilogue: out ----------------
    {
        float* Ob = Og + headoff + (size_t)(q0 + w * 16 + g * 4) * 64 + l15;
        #pragma unroll
        for (int r = 0; r < 4; ++r) {
            Ob[(size_t)r * 64 + 0]  = o0[r];
            Ob[(size_t)r * 64 + 16] = o1[r];
            Ob[(size_t)r * 64 + 32] = o2[r];
            Ob[(size_t)r * 64 + 48] = o3[r];
        }
    }
}

extern "C" void kernel_launch(void* const* d_in, const int* in_sizes, int n_in,
                              void* d_out, int out_size, void* d_ws, size_t ws_size,
                              hipStream_t stream)
{
    (void)in_sizes; (void)n_in; (void)out_size; (void)d_ws; (void)ws_size;
    const float* Q = (const float*)d_in[0];
    const float* K = (const float*)d_in[1];
    const float* V = (const float*)d_in[2];
    const int*   M = (const int*)d_in[3];
    float* Out = (float*)d_out;
    float* P   = Out + (size_t)2 * H_HEADS * S_LEN * 64;   // p_attn after out

    attn_fused<<<dim3(768), 256, 0, stream>>>(Q, K, V, M, Out, P);
}

// Round 6
// 156.747 us; speedup vs baseline: 2.4042x; 1.0392x over previous
//
#include <hip/hip_runtime.h>
#include <stdint.h>

// Attention fwd, B=2 H=12 S=2048 D=64, f32 in/out, outputs (out, p_attn).
// R6: fp16 datapath. fp16 (2^-11) is accurate enough for single-MFMA QK^T
// (split-bf16 removed: 24->16 MFMA/tile, KlS gone, conversions via native
// cvt+pack). Q A-frags direct from global. R5 skeleton kept: LDS-staged K/V,
// reg prefetch, raw lgkm-only barriers (no vmcnt drain), XCD swizzle, NT
// p-stores.

#define H_HEADS 12
#define S_LEN   2048
#define NKT     32          // S/64 K-tiles
#define L2E     1.4426950408889634f
#define NEGL2E  (-1.4426950408889634e9f)   // -1e9 * log2(e)

typedef _Float16 f16x8 __attribute__((ext_vector_type(8)));
typedef _Float16 f16x2 __attribute__((ext_vector_type(2)));
typedef float    f32x4 __attribute__((ext_vector_type(4)));

// pack two f32 -> one dword of 2x fp16 (RNE): 2x v_cvt_f16_f32 + v_pack_b32_f16
static __device__ __forceinline__ unsigned pk(float a, float b) {
    f16x2 t; t[0] = (_Float16)a; t[1] = (_Float16)b;
    return __builtin_bit_cast(unsigned, t);
}

#define MFMA(a, b, c) __builtin_amdgcn_mfma_f32_16x16x32_f16((a), (b), (c), 0, 0, 0)

// Raw barrier: LDS ordering only, no vmcnt drain (stores/loads stay in flight).
#define BAR_LGKM() asm volatile("s_waitcnt lgkmcnt(0)\n\ts_barrier" ::: "memory")

__global__ __launch_bounds__(256, 4)
void attn_fused(const float* __restrict__ Qg, const float* __restrict__ Kg,
                const float* __restrict__ Vg, const int* __restrict__ Mg,
                float* __restrict__ Og, float* __restrict__ Pg)
{
    // bufA: bytes [0,8192) = V tile (B-frag layout, fp16)
    //       bytes [8192,16384) = P staging (fp16, swizzled rows)
    __shared__ __align__(16) unsigned short bufA[8192];   // 16 KB
    __shared__ __align__(16) unsigned short KhS[4096];    // 8 KB K tile (fp16, swizzled)
    __shared__ float madd_s[64];                          // 256 B per-tile mask addend

    const int tid  = threadIdx.x;
    const int lane = tid & 63;
    const int w    = tid >> 6;       // wave 0..3 -> q rows [w*16, w*16+16)
    const int l15  = lane & 15;
    const int g    = lane >> 4;      // 0..3

    // XCD swizzle: 768 blocks, 8 XCDs, 96 blocks/XCD = 3 whole heads per XCD
    const int bid = blockIdx.x;
    const int wgs = (bid & 7) * 96 + (bid >> 3);
    const int bh  = wgs >> 5;        // 0..23
    const int qt  = wgs & 31;        // 0..31
    const int b   = bh / H_HEADS;
    const int q0  = qt * 64;

    const size_t headoff = (size_t)bh * (S_LEN * 64);
    const float* Qp = Qg + headoff;
    const float* Kp = Kg + headoff;
    const float* Vp = Vg + headoff;
    const int*   Mp = Mg + b * S_LEN;

    // ---------------- Q A-frags direct from global (x0.125) ----------------
    f16x8 aq[2];
    {
        const float* qrow = Qp + (size_t)(q0 + w * 16 + l15) * 64 + g * 8;
        #pragma unroll
        for (int kk = 0; kk < 2; ++kk) {
            float4 qa = *reinterpret_cast<const float4*>(qrow + kk * 32);
            float4 qb = *reinterpret_cast<const float4*>(qrow + kk * 32 + 4);
            aq[kk][0] = (_Float16)(qa.x * 0.125f); aq[kk][1] = (_Float16)(qa.y * 0.125f);
            aq[kk][2] = (_Float16)(qa.z * 0.125f); aq[kk][3] = (_Float16)(qa.w * 0.125f);
            aq[kk][4] = (_Float16)(qb.x * 0.125f); aq[kk][5] = (_Float16)(qb.y * 0.125f);
            aq[kk][6] = (_Float16)(qb.z * 0.125f); aq[kk][7] = (_Float16)(qb.w * 0.125f);
        }
    }

    float4 kq[4];       // K-tile prefetch registers
    float  vv[16];      // V-tile prefetch registers
    float  mv = 0.f;    // mask prefetch (tid < 64)

    // ================= sweep 1: l = sum over keys of exp(s) =================
    // prologue: load tile 0, write it, issue tile 1
    {
        const float4* src = reinterpret_cast<const float4*>(Kp);
        kq[0] = src[tid]; kq[1] = src[256 + tid]; kq[2] = src[512 + tid]; kq[3] = src[768 + tid];
        if (tid < 64) mv = Mp[tid] ? 0.0f : NEGL2E;
    }
    {
        #pragma unroll
        for (int i = 0; i < 4; ++i) {
            int e = i * 256 + tid, row = e >> 4;
            int byte = (row * 128 + (e & 15) * 8) ^ ((row & 7) << 4);
            float4 v = kq[i];
            *reinterpret_cast<uint2*>(reinterpret_cast<char*>(KhS) + byte) =
                make_uint2(pk(v.x, v.y), pk(v.z, v.w));
        }
        if (tid < 64) madd_s[tid] = mv;
    }
    {
        const float4* src = reinterpret_cast<const float4*>(Kp + 4096);
        kq[0] = src[tid]; kq[1] = src[256 + tid]; kq[2] = src[512 + tid]; kq[3] = src[768 + tid];
        mv = 0.f;
        if (tid < 64) mv = Mp[64 + tid] ? 0.0f : NEGL2E;
    }
    __syncthreads();

    float ls0 = 0.f, ls1 = 0.f, ls2 = 0.f, ls3 = 0.f;
    for (int kt = 0; kt < NKT; ++kt) {
        // ---- compute tile kt from LDS ----
        {
            const int sw = (l15 & 7) << 4;
            #pragma unroll
            for (int ct = 0; ct < 4; ++ct) {
                f32x4 acc = {0.f, 0.f, 0.f, 0.f};
                #pragma unroll
                for (int kk = 0; kk < 2; ++kk) {
                    int byte = ((ct * 16 + l15) * 128 + kk * 64 + g * 16) ^ sw;
                    f16x8 bk = *reinterpret_cast<const f16x8*>(reinterpret_cast<const char*>(KhS) + byte);
                    acc = MFMA(aq[kk], bk, acc);
                }
                float ma = madd_s[ct * 16 + l15];
                ls0 += __builtin_amdgcn_exp2f(__builtin_fmaf(acc[0], L2E, ma));
                ls1 += __builtin_amdgcn_exp2f(__builtin_fmaf(acc[1], L2E, ma));
                ls2 += __builtin_amdgcn_exp2f(__builtin_fmaf(acc[2], L2E, ma));
                ls3 += __builtin_amdgcn_exp2f(__builtin_fmaf(acc[3], L2E, ma));
            }
        }
        BAR_LGKM();        // reads(kt) done; NO vmcnt drain
        if (kt + 1 < NKT) {
            // ---- write tile kt+1 from regs (use-site vmcnt waits on kq) ----
            #pragma unroll
            for (int i = 0; i < 4; ++i) {
                int e = i * 256 + tid, row = e >> 4;
                int byte = (row * 128 + (e & 15) * 8) ^ ((row & 7) << 4);
                float4 v = kq[i];
                *reinterpret_cast<uint2*>(reinterpret_cast<char*>(KhS) + byte) =
                    make_uint2(pk(v.x, v.y), pk(v.z, v.w));
            }
            if (tid < 64) madd_s[tid] = mv;
            BAR_LGKM();    // writes(kt+1) visible
            if (kt + 2 < NKT) {
                // ---- issue loads for tile kt+2 (fly across next compute) ----
                const float4* src = reinterpret_cast<const float4*>(Kp + (size_t)(kt + 2) * 4096);
                kq[0] = src[tid]; kq[1] = src[256 + tid]; kq[2] = src[512 + tid]; kq[3] = src[768 + tid];
                mv = 0.f;
                if (tid < 64) mv = Mp[(kt + 2) * 64 + tid] ? 0.0f : NEGL2E;
            }
        }
    }
    #pragma unroll
    for (int m = 1; m <= 8; m <<= 1) {
        ls0 += __shfl_xor(ls0, m);
        ls1 += __shfl_xor(ls1, m);
        ls2 += __shfl_xor(ls2, m);
        ls3 += __shfl_xor(ls3, m);
    }
    const float li0 = 1.0f / ls0, li1 = 1.0f / ls1, li2 = 1.0f / ls2, li3 = 1.0f / ls3;

    // ================= sweep 2: p = exp(s)/l, PV =================
    f32x4 o0 = {0,0,0,0}, o1 = {0,0,0,0}, o2 = {0,0,0,0}, o3 = {0,0,0,0};
    float* Pout = Pg + ((size_t)bh * S_LEN + q0) * S_LEN;

    // prologue: load tile 0, write it, issue tile 1
    {
        const float4* src = reinterpret_cast<const float4*>(Kp);
        kq[0] = src[tid]; kq[1] = src[256 + tid]; kq[2] = src[512 + tid]; kq[3] = src[768 + tid];
        const float* vsrc  = Vp + (size_t)(w * 8) * 64 + lane;
        const float* vsrc2 = Vp + (size_t)((w + 4) * 8) * 64 + lane;
        #pragma unroll
        for (int j = 0; j < 8; ++j) { vv[j] = vsrc[j * 64]; vv[8 + j] = vsrc2[j * 64]; }
        mv = 0.f;
        if (tid < 64) mv = Mp[tid] ? 0.0f : NEGL2E;
    }
    {
        #pragma unroll
        for (int i = 0; i < 4; ++i) {
            int e = i * 256 + tid, row = e >> 4;
            int byte = (row * 128 + (e & 15) * 8) ^ ((row & 7) << 4);
            float4 v = kq[i];
            *reinterpret_cast<uint2*>(reinterpret_cast<char*>(KhS) + byte) =
                make_uint2(pk(v.x, v.y), pk(v.z, v.w));
        }
        #pragma unroll
        for (int gi = 0; gi < 2; ++gi) {
            int gv = w + gi * 4;
            *reinterpret_cast<uint4*>(reinterpret_cast<char*>(bufA) + (gv * 64 + lane) * 16) =
                make_uint4(pk(vv[gi*8+0], vv[gi*8+1]), pk(vv[gi*8+2], vv[gi*8+3]),
                           pk(vv[gi*8+4], vv[gi*8+5]), pk(vv[gi*8+6], vv[gi*8+7]));
        }
        if (tid < 64) madd_s[tid] = mv;
    }
    {
        const float4* src = reinterpret_cast<const float4*>(Kp + 4096);
        kq[0] = src[tid]; kq[1] = src[256 + tid]; kq[2] = src[512 + tid]; kq[3] = src[768 + tid];
        const float* vsrc  = Vp + (size_t)(64 + w * 8) * 64 + lane;
        const float* vsrc2 = Vp + (size_t)(64 + (w + 4) * 8) * 64 + lane;
        #pragma unroll
        for (int j = 0; j < 8; ++j) { vv[j] = vsrc[j * 64]; vv[8 + j] = vsrc2[j * 64]; }
        mv = 0.f;
        if (tid < 64) mv = Mp[64 + tid] ? 0.0f : NEGL2E;
    }
    __syncthreads();

    for (int kt = 0; kt < NKT; ++kt) {
        // ---- compute tile kt: QK^T, exp, NT p-stores, P->LDS, PV ----
        {
            const int sw = (l15 & 7) << 4;
            #pragma unroll
            for (int ct = 0; ct < 4; ++ct) {
                f32x4 acc = {0.f, 0.f, 0.f, 0.f};
                #pragma unroll
                for (int kk = 0; kk < 2; ++kk) {
                    int byte = ((ct * 16 + l15) * 128 + kk * 64 + g * 16) ^ sw;
                    f16x8 bk = *reinterpret_cast<const f16x8*>(reinterpret_cast<const char*>(KhS) + byte);
                    acc = MFMA(aq[kk], bk, acc);
                }
                float ma = madd_s[ct * 16 + l15];
                float p0 = __builtin_amdgcn_exp2f(__builtin_fmaf(acc[0], L2E, ma)) * li0;
                float p1 = __builtin_amdgcn_exp2f(__builtin_fmaf(acc[1], L2E, ma)) * li1;
                float p2 = __builtin_amdgcn_exp2f(__builtin_fmaf(acc[2], L2E, ma)) * li2;
                float p3 = __builtin_amdgcn_exp2f(__builtin_fmaf(acc[3], L2E, ma)) * li3;

                // NT global p_attn stores — never drained inside the loop
                float* Prow = Pout + (size_t)(w * 16 + g * 4) * S_LEN + (size_t)kt * 64;
                int col = ct * 16 + l15;
                __builtin_nontemporal_store(p0, Prow + col);
                __builtin_nontemporal_store(p1, Prow + S_LEN + col);
                __builtin_nontemporal_store(p2, Prow + 2 * S_LEN + col);
                __builtin_nontemporal_store(p3, Prow + 3 * S_LEN + col);

                // LDS P (fp16, A-fragment layout rows, swizzled) — wave-local
                int pb = 8192 + (w * 16 + g * 4) * 128 + (ct * 16 + l15) * 2;
                *reinterpret_cast<unsigned short*>(reinterpret_cast<char*>(bufA) + ((pb)       ^ (((g * 4 + 0) & 7) << 4))) = __builtin_bit_cast(unsigned short, (_Float16)p0);
                *reinterpret_cast<unsigned short*>(reinterpret_cast<char*>(bufA) + ((pb + 128) ^ (((g * 4 + 1) & 7) << 4))) = __builtin_bit_cast(unsigned short, (_Float16)p1);
                *reinterpret_cast<unsigned short*>(reinterpret_cast<char*>(bufA) + ((pb + 256) ^ (((g * 4 + 2) & 7) << 4))) = __builtin_bit_cast(unsigned short, (_Float16)p2);
                *reinterpret_cast<unsigned short*>(reinterpret_cast<char*>(bufA) + ((pb + 384) ^ (((g * 4 + 3) & 7) << 4))) = __builtin_bit_cast(unsigned short, (_Float16)p3);
            }
            // PV: out += P(16x64) * V(64x64)  (wave-local P)
            #pragma unroll
            for (int kk = 0; kk < 2; ++kk) {
                int abyte = 8192 + (((w * 16 + l15) * 128 + kk * 64 + g * 16) ^ ((l15 & 7) << 4));
                f16x8 ap = *reinterpret_cast<const f16x8*>(reinterpret_cast<const char*>(bufA) + abyte);
                int vb = ((kk * 4 + g) * 64 + l15) * 16;
                f16x8 bv0 = *reinterpret_cast<const f16x8*>(reinterpret_cast<const char*>(bufA) + vb);
                f16x8 bv1 = *reinterpret_cast<const f16x8*>(reinterpret_cast<const char*>(bufA) + vb + 256);
                f16x8 bv2 = *reinterpret_cast<const f16x8*>(reinterpret_cast<const char*>(bufA) + vb + 512);
                f16x8 bv3 = *reinterpret_cast<const f16x8*>(reinterpret_cast<const char*>(bufA) + vb + 768);
                o0 = MFMA(ap, bv0, o0);
                o1 = MFMA(ap, bv1, o1);
                o2 = MFMA(ap, bv2, o2);
                o3 = MFMA(ap, bv3, o3);
            }
        }
        BAR_LGKM();        // reads(kt) done; NO vmcnt drain (p-stores keep flying)
        if (kt + 1 < NKT) {
            // ---- write tile kt+1 (K, V, mask) from regs ----
            #pragma unroll
            for (int i = 0; i < 4; ++i) {
                int e = i * 256 + tid, row = e >> 4;
                int byte = (row * 128 + (e & 15) * 8) ^ ((row & 7) << 4);
                float4 v = kq[i];
                *reinterpret_cast<uint2*>(reinterpret_cast<char*>(KhS) + byte) =
                    make_uint2(pk(v.x, v.y), pk(v.z, v.w));
            }
            #pragma unroll
            for (int gi = 0; gi < 2; ++gi) {
                int gv = w + gi * 4;
                *reinterpret_cast<uint4*>(reinterpret_cast<char*>(bufA) + (gv * 64 + lane) * 16) =
                    make_uint4(pk(vv[gi*8+0], vv[gi*8+1]), pk(vv[gi*8+2], vv[gi*8+3]),
                               pk(vv[gi*8+4], vv[gi*8+5]), pk(vv[gi*8+6], vv[gi*8+7]));
            }
            if (tid < 64) madd_s[tid] = mv;
            BAR_LGKM();    // writes(kt+1) visible
            if (kt + 2 < NKT) {
                // ---- issue loads for tile kt+2 (fly across next compute) ----
                const float4* src = reinterpret_cast<const float4*>(Kp + (size_t)(kt + 2) * 4096);
                kq[0] = src[tid]; kq[1] = src[256 + tid]; kq[2] = src[512 + tid]; kq[3] = src[768 + tid];
                const float* vsrc  = Vp + (size_t)((kt + 2) * 64 + w * 8) * 64 + lane;
                const float* vsrc2 = Vp + (size_t)((kt + 2) * 64 + (w + 4) * 8) * 64 + lane;
                #pragma unroll
                for (int j = 0; j < 8; ++j) { vv[j] = vsrc[j * 64]; vv[8 + j] = vsrc2[j * 64]; }
                mv = 0.f;
                if (tid < 64) mv = Mp[(kt + 2) * 64 + tid] ? 0.0f : NEGL2E;
            }
        }
    }

    // ---------------- epilogue: out ----------------
    {
        float* Ob = Og + headoff + (size_t)(q0 + w * 16 + g * 4) * 64 + l15;
        #pragma unroll
        for (int r = 0; r < 4; ++r) {
            Ob[(size_t)r * 64 + 0]  = o0[r];
            Ob[(size_t)r * 64 + 16] = o1[r];
            Ob[(size_t)r * 64 + 32] = o2[r];
            Ob[(size_t)r * 64 + 48] = o3[r];
        }
    }
}

extern "C" void kernel_launch(void* const* d_in, const int* in_sizes, int n_in,
                              void* d_out, int out_size, void* d_ws, size_t ws_size,
                              hipStream_t stream)
{
    (void)in_sizes; (void)n_in; (void)out_size; (void)d_ws; (void)ws_size;
    const float* Q = (const float*)d_in[0];
    const float* K = (const float*)d_in[1];
    const float* V = (const float*)d_in[2];
    const int*   M = (const int*)d_in[3];
    float* Out = (float*)d_out;
    float* P   = Out + (size_t)2 * H_HEADS * S_LEN * 64;   // p_attn after out

    attn_fused<<<dim3(768), 256, 0, stream>>>(Q, K, V, M, Out, P);
}